// Round 5
// baseline (130.015 us; speedup 1.0000x reference)
//
#include <hip/hip_runtime.h>
#include <hip/hip_bf16.h>
#include <hip/hip_fp16.h>

#define N_BCH 8
#define N_ATM 10000
#define N_ELM 100
#define N_ATOMS_TOT 80000
#define NBLK 256
#define NTHR 1024

typedef int   i4 __attribute__((ext_vector_type(4)));
typedef float f4 __attribute__((ext_vector_type(4)));

// One fused kernel. Per block:
//  - stage whole elm table (int32 -> packed u8) into LDS (80 KB)
//  - stage (k,radius) as half2 (one ds_read_b32 per endpoint)
//  - process a contiguous chunk of 5000 vec4-edges in 5 coalesced sweeps,
//    prefetching sweep s+1's 4 loads while computing sweep s.
__launch_bounds__(1024, 4)
__global__ void edge_kernel(const int* __restrict__ elm,
                            const float* __restrict__ kparam,
                            const float* __restrict__ radius,
                            const int* __restrict__ edge_n,
                            const int* __restrict__ edge_i,
                            const int* __restrict__ edge_j,
                            const float* __restrict__ sod,
                            float* __restrict__ out,
                            int nE) {
    __shared__ unsigned int s_elm32[N_ATOMS_TOT / 4];  // 80000 B u8 elm table
    __shared__ __half2 s_kr[128];                      // (k,r) half2, 100 used
    __shared__ float s_red[16][N_BCH];

    // ---- stage: pack elm int32 -> u8 directly from global (L2/L3-resident) ----
    for (int t = threadIdx.x; t < N_ATOMS_TOT / 4; t += NTHR) {
        i4 v = *(const i4*)(elm + 4 * t);
        s_elm32[t] = (unsigned int)(v[0] & 0xff)
                   | ((unsigned int)(v[1] & 0xff) << 8)
                   | ((unsigned int)(v[2] & 0xff) << 16)
                   | ((unsigned int)(v[3] & 0xff) << 24);
    }
    if (threadIdx.x < N_ELM)
        s_kr[threadIdx.x] =
            __floats2half2_rn(kparam[threadIdx.x], radius[threadIdx.x]);
    __syncthreads();

    const unsigned char* s_elm = (const unsigned char*)s_elm32;

    float acc[N_BCH];
#pragma unroll
    for (int b = 0; b < N_BCH; ++b) acc[b] = 0.0f;

    const int nvec  = nE >> 2;
    const int chunk = (nvec + NBLK - 1) / NBLK;        // 5000 for nE=5.12M
    const int base  = blockIdx.x * chunk;
    const int vmax  = min(base + chunk, nvec);
    const int nsweep = (chunk + NTHR - 1) / NTHR;      // 5

    const i4* en4 = (const i4*)edge_n;
    const i4* ei4 = (const i4*)edge_i;
    const i4* ej4 = (const i4*)edge_j;
    const f4* s4  = (const f4*)sod;

    // prefetch sweep 0 (clamped index so loads are unconditional)
    int  v  = base + threadIdx.x;
    bool pv = v < vmax;
    int  vc = pv ? v : 0;
    i4 nn = __builtin_nontemporal_load(en4 + vc);
    i4 ii = __builtin_nontemporal_load(ei4 + vc);
    i4 jj = __builtin_nontemporal_load(ej4 + vc);
    f4 ss = __builtin_nontemporal_load(s4  + vc);

    for (int s = 0; s < nsweep; ++s) {
        // prefetch next sweep
        int  v2  = v + NTHR;
        bool pv2 = v2 < vmax;
        int  vc2 = pv2 ? v2 : 0;
        i4 nn2 = __builtin_nontemporal_load(en4 + vc2);
        i4 ii2 = __builtin_nontemporal_load(ei4 + vc2);
        i4 jj2 = __builtin_nontemporal_load(ej4 + vc2);
        f4 ss2 = __builtin_nontemporal_load(s4  + vc2);

        // process current sweep (pv masks the clamped lanes)
#pragma unroll
        for (int u = 0; u < 4; ++u) {
            int n = nn[u];
            int bb = n * N_ATM;
            int e_i = s_elm[bb + ii[u]];
            int e_j = s_elm[bb + jj[u]];
            __half2 krsum = __hadd2(s_kr[e_i], s_kr[e_j]);
            float kk = __low2float(krsum);
            float R  = __high2float(krsum);
            float dis = sqrtf(ss[u]);
            float d  = dis - R;
            float val = (pv && (dis < R)) ? kk * d * d : 0.0f;
#pragma unroll
            for (int b = 0; b < N_BCH; ++b)
                acc[b] += (n == b) ? val : 0.0f;
        }
        nn = nn2; ii = ii2; jj = jj2; ss = ss2; v = v2; pv = pv2;
    }

    // scalar tail (nE % 4): first few global threads
    const int tail_start = nvec << 2;
    const int tail_n = nE - tail_start;
    const int gtid = blockIdx.x * NTHR + threadIdx.x;
    if (gtid < tail_n) {
        int e = tail_start + gtid;
        int n = edge_n[e];
        int e_i = s_elm[n * N_ATM + edge_i[e]];
        int e_j = s_elm[n * N_ATM + edge_j[e]];
        __half2 krsum = __hadd2(s_kr[e_i], s_kr[e_j]);
        float kk = __low2float(krsum);
        float R  = __high2float(krsum);
        float dis = sqrtf(sod[e]);
        float d  = dis - R;
        float val = (dis < R) ? kk * d * d : 0.0f;
#pragma unroll
        for (int b = 0; b < N_BCH; ++b)
            acc[b] += (n == b) ? val : 0.0f;
    }

    // ---- two-phase wave reduction ----
    const int lane = threadIdx.x & 63;
    const int wave = threadIdx.x >> 6;   // 16 waves
#pragma unroll
    for (int off = 8; off <= 32; off <<= 1) {
#pragma unroll
        for (int b = 0; b < N_BCH; ++b)
            acc[b] += __shfl_xor(acc[b], off, 64);
    }
    const int j = lane >> 3;
    float x = acc[0];
#pragma unroll
    for (int b = 1; b < N_BCH; ++b) x = (j == b) ? acc[b] : x;
#pragma unroll
    for (int off = 1; off <= 4; off <<= 1)
        x += __shfl_xor(x, off, 64);

    if ((lane & 7) == 0) s_red[wave][j] = x;
    __syncthreads();
    if (threadIdx.x < N_BCH) {
        float t = 0.0f;
#pragma unroll
        for (int w = 0; w < 16; ++w) t += s_red[w][threadIdx.x];
        atomicAdd(&out[threadIdx.x], t);
    }
}

extern "C" void kernel_launch(void* const* d_in, const int* in_sizes, int n_in,
                              void* d_out, int out_size, void* d_ws, size_t ws_size,
                              hipStream_t stream) {
    const int*   elm    = (const int*)d_in[0];
    const int*   edge_n = (const int*)d_in[1];
    const int*   edge_i = (const int*)d_in[2];
    const int*   edge_j = (const int*)d_in[3];
    const float* sod    = (const float*)d_in[4];
    const float* kparam = (const float*)d_in[5];
    const float* radius = (const float*)d_in[6];
    float* out = (float*)d_out;
    const int nE = in_sizes[1];

    // graph-capture-legal async memset of the 8 output accumulators
    hipMemsetAsync(out, 0, out_size * sizeof(float), stream);

    // 256 blocks x 1024 thr: exactly 1 block/CU, uniform 5000 vec4s per block
    hipLaunchKernelGGL(edge_kernel, dim3(NBLK), dim3(NTHR), 0, stream,
                       elm, kparam, radius, edge_n, edge_i, edge_j, sod,
                       out, nE);
}